// Round 2
// baseline (280.401 us; speedup 1.0000x reference)
//
#include <hip/hip_runtime.h>

// Problem constants: B=16, S=4096, H=768, T=2000
#define BB 16
#define SS 4096
#define HH 768
#define TT 2000
#define HV (HH / 4)          // 192 float4 per row
#define TPB 16               // tokens per block (4 waves x 4 tokens)
#define BPB (TT / TPB)       // 125 blocks per batch (2000 % 16 == 0)

typedef float vf4 __attribute__((ext_vector_type(4)));

// ---------------------------------------------------------------------------
// Kernel 1: per-batch exclusive prefix sum of subtoken_lengths, +1 offset,
// packed as (start << 2) | len  (start <= 4001 fits 12 bits, len in {0,1,2}).
// NO WORKSPACE: the packed metadata is stashed in the first 4 bytes of each
// token's own output row (out[b,t,0] reinterpreted as int). Kernel 2 reads it
// back (stream-ordered) and overwrites the whole row, so the final output is
// untouched by this trick.
// ---------------------------------------------------------------------------
__global__ __launch_bounds__(256) void tokrep_scan_kernel(
    const int4* __restrict__ lens4, int* __restrict__ outi) {
    __shared__ int sums[256];
    const int b = blockIdx.x;
    const int tid = threadIdx.x;

    int L[8];
    int v[8];
    int s = 0;
    if (tid < 250) {
        int4 a = lens4[b * 500 + tid * 2];
        int4 c = lens4[b * 500 + tid * 2 + 1];
        L[0] = a.x; L[1] = a.y; L[2] = a.z; L[3] = a.w;
        L[4] = c.x; L[5] = c.y; L[6] = c.z; L[7] = c.w;
#pragma unroll
        for (int i = 0; i < 8; ++i) { v[i] = s; s += L[i]; }
    }
    sums[tid] = s;
    __syncthreads();

    // Hillis-Steele inclusive scan over the 256 chunk sums
    for (int off = 1; off < 256; off <<= 1) {
        int x = (tid >= off) ? sums[tid - off] : 0;
        __syncthreads();
        if (tid >= off) sums[tid] += x;
        __syncthreads();
    }

    if (tid < 250) {
        const int base = 1 + ((tid == 0) ? 0 : sums[tid - 1]);
        int* dst = outi + (size_t)(b * TT + tid * 8) * HH;  // out[b, t, 0]
#pragma unroll
        for (int i = 0; i < 8; ++i)
            dst[(size_t)i * HH] = ((base + v[i]) << 2) | L[i];
    }
}

// ---------------------------------------------------------------------------
// Kernel 2: pooled[b,t,:] = len==0 ? 0 : mean(hidden[b, start:start+len, :])
// One 64-lane wave owns one full token row (lane l covers float4 slots
// {l, l+64, l+128}); each wave handles 4 consecutive tokens. Metadata comes
// from the stash in out[b,t,0] (uniform-address load + readfirstlane ->
// scalar branches). ALL loads for the 4 tokens are issued before any
// combine/store, so up to 24 x 16B loads are in flight per wave with no
// intermediate vmcnt drains.
// ---------------------------------------------------------------------------
__global__ __launch_bounds__(256) void tokrep_pool_kernel(
    const vf4* __restrict__ hs, vf4* __restrict__ out) {
    const int wave = threadIdx.x >> 6;
    const int lane = threadIdx.x & 63;
    const int b    = blockIdx.x / BPB;                 // const div -> magic mul
    const int t0   = (blockIdx.x - b * BPB) * TPB;
    const int bt0  = b * TT + t0 + wave * 4;           // this wave's 4 tokens

    // Fetch the 4 stashed metadata words (uniform address per wave -> one
    // broadcast request each), then scalarize.
    const int* meta = (const int*)(out + (size_t)bt0 * HV);
    int pk[4];
#pragma unroll
    for (int it = 0; it < 4; ++it)
        pk[it] = __builtin_amdgcn_readfirstlane(meta[(size_t)it * HH]);

    const vf4* __restrict__ hb = hs + (size_t)b * (SS * HV);

    // ---- load phase: issue everything, combine nothing ----
    vf4 a[4][3], c[4][3];
#pragma unroll
    for (int it = 0; it < 4; ++it) {
        const int len   = pk[it] & 3;
        const int start = pk[it] >> 2;
        const vf4* row  = hb + (size_t)start * HV + lane;
        if (len != 0) {
            a[it][0] = __builtin_nontemporal_load(row);
            a[it][1] = __builtin_nontemporal_load(row + 64);
            a[it][2] = __builtin_nontemporal_load(row + 128);
        } else {
            a[it][0] = (vf4)(0.f); a[it][1] = (vf4)(0.f); a[it][2] = (vf4)(0.f);
        }
        if (len == 2) {
            c[it][0] = __builtin_nontemporal_load(row + HV);
            c[it][1] = __builtin_nontemporal_load(row + HV + 64);
            c[it][2] = __builtin_nontemporal_load(row + HV + 128);
        } else {
            c[it][0] = (vf4)(0.f); c[it][1] = (vf4)(0.f); c[it][2] = (vf4)(0.f);
        }
    }

    // ---- combine + store phase ----
    vf4* ob = out + (size_t)bt0 * HV + lane;
#pragma unroll
    for (int it = 0; it < 4; ++it) {
        const float w = (pk[it] & 2) ? 0.5f : 1.0f;   // len==2 -> mean
        vf4 r0 = (a[it][0] + c[it][0]) * w;
        vf4 r1 = (a[it][1] + c[it][1]) * w;
        vf4 r2 = (a[it][2] + c[it][2]) * w;
        vf4* o = ob + it * HV;
        __builtin_nontemporal_store(r0, o);
        __builtin_nontemporal_store(r1, o + 64);
        __builtin_nontemporal_store(r2, o + 128);
    }
}

// ---------------------------------------------------------------------------
extern "C" void kernel_launch(void* const* d_in, const int* in_sizes, int n_in,
                              void* d_out, int out_size, void* d_ws, size_t ws_size,
                              hipStream_t stream) {
    const float* hs = (const float*)d_in[0];   // (B,S,H) fp32
    const int* lens = (const int*)d_in[1];     // (B,T) int32
    float* out      = (float*)d_out;           // (B,T,H) fp32
    // d_ws deliberately unused: workspace re-poison fills dominated the
    // previous measurement (2 x 768 MB fillBuffer per iteration).

    tokrep_scan_kernel<<<BB, 256, 0, stream>>>((const int4*)lens, (int*)out);

    tokrep_pool_kernel<<<BB * BPB, 256, 0, stream>>>(
        (const vf4*)hs, (vf4*)out);
}